// Round 12
// baseline (31.812 us; speedup 1.0000x reference)
//
#include <hip/hip_runtime.h>
#include <math.h>

#define HW (1024*1024)
#define BATCH 16

// Kernel 1: per-(batch,channel) complex affine params -> d_ws (768 B).
// Fold: caddmul(clerp(w0,w1,l), s, bias) = w0*s*(1-l) + w1*s*l + bias,
// so A = s*(1-l), B = s*l, C = bias.  par: [16][2][6] = {Ar,Ai,Br,Bi,Cr,Ci}
__global__ __launch_bounds__(192) void params_kernel(
    const float* __restrict__ x,       // [16][64]
    const float* __restrict__ W_in,    // [12][64]
    const float* __restrict__ b_in,    // [12]
    const float* __restrict__ W_gate,  // [12][64]
    const float* __restrict__ b_gate,  // [12]
    float* __restrict__ par)           // [16][2][6]
{
    __shared__ float smod[BATCH][12];
    int t = threadIdx.x;
    int b = t / 12, j = t % 12;
    {
        const float4* x4  = (const float4*)(x + b * 64);
        const float4* wi4 = (const float4*)(W_in + j * 64);
        const float4* wg4 = (const float4*)(W_gate + j * 64);
        float xt = b_in[j], xg = b_gate[j];
#pragma unroll
        for (int k = 0; k < 16; ++k) {
            float4 xv = x4[k], wi = wi4[k], wg = wg4[k];
            xt = fmaf(xv.x, wi.x, xt); xg = fmaf(xv.x, wg.x, xg);
            xt = fmaf(xv.y, wi.y, xt); xg = fmaf(xv.y, wg.y, xg);
            xt = fmaf(xv.z, wi.z, xt); xg = fmaf(xv.z, wg.z, xg);
            xt = fmaf(xv.w, wi.w, xt); xg = fmaf(xv.w, wg.w, xg);
        }
        smod[b][j] = xt * tanhf(xg);
    }
    __syncthreads();
    if (t < 32) {
        int bb = t >> 1, c = t & 1;
        float l0 = smod[bb][0 + c * 2 + 0] + 0.5f;
        float l1 = smod[bb][0 + c * 2 + 1];
        float br = smod[bb][4 + c * 2 + 0];
        float bi = smod[bb][4 + c * 2 + 1];
        float s0 = smod[bb][8 + c * 2 + 0] + 1.0f;
        float s1 = smod[bb][8 + c * 2 + 1];
        float omr = 1.0f - l0, omi = -l1;      // (1 - l)
        float Ar = s0 * omr - s1 * omi;
        float Ai = s0 * omi + s1 * omr;
        float Br = s0 * l0 - s1 * l1;
        float Bi = s0 * l1 + s1 * l0;
        float* p = par + (bb * 2 + c) * 6;
        p[0] = Ar; p[1] = Ai; p[2] = Br; p[3] = Bi; p[4] = br; p[5] = bi;
    }
}

// Compute batches [b0,b1) for one 2-px chunk held in W[4] (one float4 per jc:
// {px0.re, px0.im, px1.re, px1.im}), storing float2 per batch.
__device__ __forceinline__ void do_batches(
    const float4* __restrict__ W, const float* __restrict__ par,
    float2* __restrict__ out2, int idx, int b0, int b1)
{
#pragma unroll
    for (int b = b0; b < b1; ++b) {
        const float* p0 = par + (b * 2 + 0) * 6;   // uniform -> s_load, hoisted
        const float* p1 = par + (b * 2 + 1) * 6;
        float A0r = p0[0], A0i = p0[1], B0r = p0[2], B0i = p0[3], c0r = p0[4], c0i = p0[5];
        float A1r = p1[0], A1i = p1[1], B1r = p1[2], B1i = p1[3], c1r = p1[4], c1i = p1[5];
        float2 o;
        // px0: .x/.y of each plane
        {
            float z0r = c0r + A0r * W[0].x - A0i * W[0].y + B0r * W[2].x - B0i * W[2].y;
            float z0i = c0i + A0r * W[0].y + A0i * W[0].x + B0r * W[2].y + B0i * W[2].x;
            float z1r = c1r + A1r * W[1].x - A1i * W[1].y + B1r * W[3].x - B1i * W[3].y;
            float z1i = c1i + A1r * W[1].y + A1i * W[1].x + B1r * W[3].y + B1i * W[3].x;
            float rs = rsqrtf(z1r * z1r + z1i * z1i + 1e-12f);
            o.x = (z0r * z1r + z0i * z1i) * rs;
        }
        // px1: .z/.w of each plane
        {
            float z0r = c0r + A0r * W[0].z - A0i * W[0].w + B0r * W[2].z - B0i * W[2].w;
            float z0i = c0i + A0r * W[0].w + A0i * W[0].z + B0r * W[2].w + B0i * W[2].z;
            float z1r = c1r + A1r * W[1].z - A1i * W[1].w + B1r * W[3].z - B1i * W[3].w;
            float z1i = c1i + A1r * W[1].w + A1i * W[1].z + B1r * W[3].w + B1i * W[3].z;
            float rs = rsqrtf(z1r * z1r + z1i * z1i + 1e-12f);
            o.y = (z0r * z1r + z0i * z1i) * rs;
        }
        out2[b * (HW / 2) + idx] = o;
    }
}

// Kernel 2: streaming transform with STAGGERED reads. Each thread owns two
// 2-px chunks (disjoint halves of HW). Chunk-1 loads are issued midway
// through chunk-0 compute (sched_barrier pins them there), so the read
// stream overlaps the store stream instead of front-loading all reads
// into a serial ~5us read phase followed by a write-only phase.
__global__ __launch_bounds__(256) void main_kernel(
    const float* __restrict__ wts,   // [2][2][HW][2]
    const float* __restrict__ par,   // [16][2][6] = 192 floats
    float* __restrict__ out)         // [16][HW]
{
    const int t = threadIdx.x;
    const int i0 = blockIdx.x * 256 + t;     // chunk 0: 0 .. HW/4-1
    const int i1 = i0 + (HW / 4);            // chunk 1: HW/4 .. HW/2-1
    const float4* w4 = (const float4*)wts;   // [jc][HW/2] float4s
    float2* out2 = (float2*)out;

    float4 WA[4];
#pragma unroll
    for (int jc = 0; jc < 4; ++jc) WA[jc] = w4[jc * (HW / 2) + i0];

    // first half of chunk-0 batches (8 stores) while nothing else is in flight
    do_batches(WA, par, out2, i0, 0, 8);

    // pin chunk-1 loads HERE: reads now fly while chunk-0 stores continue
    __builtin_amdgcn_sched_barrier(0);
    float4 WB[4];
#pragma unroll
    for (int jc = 0; jc < 4; ++jc) WB[jc] = w4[jc * (HW / 2) + i1];

    do_batches(WA, par, out2, i0, 8, 16);
    do_batches(WB, par, out2, i1, 0, 16);
}

extern "C" void kernel_launch(void* const* d_in, const int* in_sizes, int n_in,
                              void* d_out, int out_size, void* d_ws, size_t ws_size,
                              hipStream_t stream) {
    const float* x      = (const float*)d_in[0];
    const float* W_in   = (const float*)d_in[1];
    const float* b_in   = (const float*)d_in[2];
    const float* W_gate = (const float*)d_in[3];
    const float* b_gate = (const float*)d_in[4];
    const float* wts    = (const float*)d_in[5];
    float* out = (float*)d_out;
    float* par = (float*)d_ws;

    params_kernel<<<1, 192, 0, stream>>>(x, W_in, b_in, W_gate, b_gate, par);
    main_kernel<<<1024, 256, 0, stream>>>(wts, par, out);
}